// Round 23
// baseline (5616.795 us; speedup 1.0000x reference)
//
#include <hip/hip_runtime.h>
#include <cstdint>

typedef unsigned long long u64;
typedef unsigned int u32;

__device__ inline u32 fmono(float f){ u32 u = __float_as_uint(f); u32 m = (u & 0x80000000u) ? 0xFFFFFFFFu : 0x80000000u; return u ^ m; }

__device__ const int    g_H[4]       = {160, 80, 40, 20};
__device__ const int    g_strideI[4] = {4, 8, 16, 32};
__device__ const float  g_size[4]    = {32.f, 64.f, 128.f, 256.f};
__device__ const int    g_cofs[4]    = {0, 76800, 96000, 100800};
__device__ const int    g_cnt[4]     = {76800, 19200, 4800, 1200};
__device__ const int    c_blkBase[5] = {0, 1600, 2000, 2288, 2416};
__device__ const int    c_S[4]       = {4, 4, 8, 8};
__device__ const int    c_pofs[4]    = {0, 25600, 32000, 33600};
__device__ const size_t c_partofs[4] = {0, 26214400, 32768000, 36044800};

// ---------------- prep: weight transpose (blocks 0..575) + head-weight concat (blocks 576..995)
__global__ __launch_bounds__(256) void prep_k(const float* __restrict__ w, float* __restrict__ wT,
  const float* __restrict__ cls_w, const float* __restrict__ cls_b,
  const float* __restrict__ bbox_w, const float* __restrict__ bbox_b,
  float* __restrict__ wcat, float* __restrict__ bcat)
{
  int b = blockIdx.x;
  if (b < 576){
    __shared__ float tile[32][33];
    int tx = threadIdx.x & 31, ty = threadIdx.x >> 5;
    int row0 = (b % 72)*32, co0 = (b / 72)*32;
    #pragma unroll
    for (int r=0;r<4;r++){
      int co = co0 + ty + r*8;
      tile[ty+r*8][tx] = w[(size_t)co*2304 + row0 + tx];
    }
    __syncthreads();
    #pragma unroll
    for (int r=0;r<4;r++){
      int row = row0 + ty + r*8;
      wT[(size_t)row*256 + co0 + tx] = tile[tx][ty+r*8];
    }
  } else {
    int t = (b-576)*256 + threadIdx.x;
    if (t < 105*1024){ int o = t >> 10, k = t & 1023; wcat[t] = (o < 21) ? cls_w[o*1024+k] : bbox_w[(o-21)*1024+k]; }
    if (t < 105) bcat[t] = (t < 21) ? cls_b[t] : bbox_b[t-21];
  }
}

// ---------------- fused 3x3 conv over ALL levels (single-buffer; occupancy-capped VGPR).
#define KC 4
__global__ __launch_bounds__(256, 6) void rpn_conv_all_k(
    const float* __restrict__ p0, const float* __restrict__ p1,
    const float* __restrict__ p2f, const float* __restrict__ p3f,
    const float* __restrict__ wT, float* __restrict__ convp)
{
  int bid = blockIdx.x;
  int lvl = (bid >= c_blkBase[1]) + (bid >= c_blkBase[2]) + (bid >= c_blkBase[3]);
  int local = bid - c_blkBase[lvl];
  int nz  = c_S[lvl];
  int H = g_H[lvl], W = H;
  const float* in = (lvl==0)?p0:((lvl==1)?p1:((lvl==2)?p2f:p3f));
  float* part = convp + c_partofs[lvl];
  int zb   = local % nz;
  int cb   = (local / nz) & 3;
  int tile = local / (nz*4);

  int tilesX = (W + 15) >> 4;
  int tr0 = (tile / tilesX) * 16;
  int tc0 = (tile % tilesX) * 16;
  int ciPer = 256 / nz;
  int ciBeg = zb * ciPer;
  int t   = threadIdx.x;
  int tco = t & 15, tp = t >> 4;
  int pr = (tp >> 2) * 4, pc = (tp & 3) * 4;
  int HW = H*W;

  __shared__ float sIn[KC][18][20];
  __shared__ float sW[KC*9][64];

  float* sInF = &sIn[0][0][0];
  float* sWF  = &sW[0][0];

  int   iOff[6]; int iLds[6]; bool iOk[6];
  #pragma unroll
  for (int s=0;s<6;s++){
    int e = t + s*256;
    bool a = (s<5) || (t < (KC*324 - 5*256));
    int ee = a ? e : 0;
    int c = ee/324, r2 = ee%324, row = r2/18, col = r2%18;
    int gy = tr0+row-1, gx = tc0+col-1;
    bool ok = a && ((unsigned)gy < (unsigned)H) && ((unsigned)gx < (unsigned)W);
    iOff[s] = c*HW + gy*W + gx;
    iLds[s] = c*360 + row*20 + col;
    iOk[s]  = ok;
  }
  bool iAct5 = (t < (KC*324 - 5*256));
  int wOff[3]; int wLds[3];
  #pragma unroll
  for (int s=0;s<3;s++){
    int e4 = t + s*256;
    bool a = (s<2) || (t < (KC*9*16 - 2*256));
    int ee = a ? e4 : 0;
    int row = ee>>4, c4 = (ee&15)<<2;
    wOff[s] = row*256 + cb*64 + c4;
    wLds[s] = row*64 + c4;
  }
  bool wAct2 = (t < (KC*9*16 - 2*256));

  float acc[4][16];
  #pragma unroll
  for (int o=0;o<4;o++)
    #pragma unroll
    for (int p=0;p<16;p++) acc[o][p]=0.f;

  float  ri0,ri1,ri2,ri3,ri4,ri5;
  float4 rw0,rw1,rw2;

  {
    const float* inb = in + (size_t)ciBeg*HW;
    const float* wb  = wT + (size_t)ciBeg*2304;
    ri0 = iOk[0] ? inb[iOff[0]] : 0.f;
    ri1 = iOk[1] ? inb[iOff[1]] : 0.f;
    ri2 = iOk[2] ? inb[iOff[2]] : 0.f;
    ri3 = iOk[3] ? inb[iOff[3]] : 0.f;
    ri4 = iOk[4] ? inb[iOff[4]] : 0.f;
    ri5 = iOk[5] ? inb[iOff[5]] : 0.f;
    rw0 = *(const float4*)&wb[wOff[0]];
    rw1 = *(const float4*)&wb[wOff[1]];
    if (wAct2) rw2 = *(const float4*)&wb[wOff[2]];
  }

  int ciEnd = ciBeg + ciPer;
  for (int ci0=ciBeg; ci0<ciEnd; ci0+=KC){
    sInF[iLds[0]] = ri0; sInF[iLds[1]] = ri1; sInF[iLds[2]] = ri2;
    sInF[iLds[3]] = ri3; sInF[iLds[4]] = ri4;
    if (iAct5) sInF[iLds[5]] = ri5;
    *(float4*)&sWF[wLds[0]] = rw0;
    *(float4*)&sWF[wLds[1]] = rw1;
    if (wAct2) *(float4*)&sWF[wLds[2]] = rw2;
    __syncthreads();

    if (ci0 + KC < ciEnd){
      const float* inb = in + (size_t)(ci0+KC)*HW;
      const float* wb  = wT + (size_t)(ci0+KC)*2304;
      ri0 = iOk[0] ? inb[iOff[0]] : 0.f;
      ri1 = iOk[1] ? inb[iOff[1]] : 0.f;
      ri2 = iOk[2] ? inb[iOff[2]] : 0.f;
      ri3 = iOk[3] ? inb[iOff[3]] : 0.f;
      ri4 = iOk[4] ? inb[iOff[4]] : 0.f;
      ri5 = iOk[5] ? inb[iOff[5]] : 0.f;
      rw0 = *(const float4*)&wb[wOff[0]];
      rw1 = *(const float4*)&wb[wOff[1]];
      if (wAct2) rw2 = *(const float4*)&wb[wOff[2]];
    }

    #pragma unroll
    for (int c=0;c<KC;c++){
      float rin[6][6];
      #pragma unroll
      for (int rr=0;rr<6;rr++){
        float4 a = *(const float4*)&sIn[c][pr+rr][pc];
        float2 b = *(const float2*)&sIn[c][pr+rr][pc+4];
        rin[rr][0]=a.x; rin[rr][1]=a.y; rin[rr][2]=a.z; rin[rr][3]=a.w;
        rin[rr][4]=b.x; rin[rr][5]=b.y;
      }
      #pragma unroll
      for (int k=0;k<9;k++){
        int ky=k/3, kx=k%3;
        float4 w0 = *(const float4*)&sW[c*9+k][tco*4];
        float wv[4] = {w0.x,w0.y,w0.z,w0.w};
        #pragma unroll
        for (int dr=0;dr<4;dr++)
          #pragma unroll
          for (int dc=0;dc<4;dc++){
            float iv = rin[dr+ky][dc+kx];
            int p = dr*4+dc;
            #pragma unroll
            for (int o=0;o<4;o++) acc[o][p] = fmaf(wv[o], iv, acc[o][p]);
          }
      }
    }
    __syncthreads();
  }

  int coBase = cb*64 + tco*4;
  float* pb = part + (size_t)zb*HW*256;
  #pragma unroll
  for (int dr=0;dr<4;dr++){
    int gy = tr0+pr+dr; if (gy>=H) continue;
    #pragma unroll
    for (int dc=0;dc<4;dc++){
      int gx = tc0+pc+dc; if (gx>=W) continue;
      int p = dr*4+dc;
      *(float4*)&pb[(size_t)(gy*W+gx)*256 + coBase] = make_float4(acc[0][p],acc[1][p],acc[2][p],acc[3][p]);
    }
  }
}

// ---------------- 1x1 heads fused with conv-reduce: reads convp directly.
__global__ __launch_bounds__(256) void rpn_heads_k(
  const float* __restrict__ convp, const float* __restrict__ cbias,
  const float* __restrict__ ow, const float* __restrict__ ob,
  const float* __restrict__ dw, const float* __restrict__ db,
  float* __restrict__ scores, float* __restrict__ deltas)
{
  __shared__ float sw[15][256];
  int t = threadIdx.x;
  for (int e=t; e<15*256; e+=256){ int o=e>>8, k=e&255; sw[o][k] = (o<3)? ow[o*256+k] : dw[(o-3)*256+k]; }
  __syncthreads();
  int wv = t>>6, lane = t&63;
  float4 bv = *(const float4*)&cbias[lane*4];
  #pragma unroll
  for (int i=0;i<16;i++){
    int gpx = blockIdx.x*64 + wv*16 + i;
    if (gpx >= 34000) return;
    int lvl = (gpx >= 25600) + (gpx >= 32000) + (gpx >= 33600);
    int S = c_S[lvl];
    size_t stride = (size_t)g_H[lvl]*g_H[lvl]*256;
    const float* pb = convp + c_partofs[lvl] + (size_t)(gpx - c_pofs[lvl])*256 + lane*4;
    float vx=0.f, vy=0.f, vz=0.f, vw=0.f;
    for (int s=0;s<S;s++){
      float4 q = *(const float4*)(pb + (size_t)s*stride);
      vx += q.x; vy += q.y; vz += q.z; vw += q.w;
    }
    vx += bv.x; vy += bv.y; vz += bv.z; vw += bv.w;
    vx = vx>0.f?vx:0.f; vy = vy>0.f?vy:0.f; vz = vz>0.f?vz:0.f; vw = vw>0.f?vw:0.f;
    float a[15];
    #pragma unroll
    for (int o=0;o<15;o++){
      const float* w = &sw[o][lane*4];
      a[o] = w[0]*vx + w[1]*vy + w[2]*vz + w[3]*vw;
    }
    #pragma unroll
    for (int off=32; off; off>>=1)
      #pragma unroll
      for (int o=0;o<15;o++) a[o] += __shfl_xor(a[o], off, 64);
    if (lane==0){
      for (int q=0;q<3;q++) scores[gpx*3+q] = a[q] + ob[q];
      for (int q=0;q<3;q++)
        for (int j=0;j<4;j++)
          deltas[(size_t)(gpx*3+q)*4 + j] = a[3+q*4+j] + db[q*4+j];
    }
  }
}

// ---------------- exact per-level top-1000: histogram + parallel suffix-scan threshold + collect + bitonic
__global__ __launch_bounds__(1024) void topk_k(
  const float* __restrict__ scores, float* __restrict__ top_s, u32* __restrict__ top_idx)
{
  int lvl = blockIdx.x;
  int base = g_cofs[lvl], N = g_cnt[lvl];
  const int K = 1000;
  __shared__ u32 hist[4096];
  __shared__ u64 sbuf[4096];
  __shared__ u32 shThr; __shared__ int scnt;
  u32* scratch = (u32*)sbuf;
  int t = threadIdx.x;
  for (int e=t; e<4096; e+=1024) hist[e]=0;
  __syncthreads();
  for (int e=t; e<N; e+=1024){
    u32 m = fmono(scores[base+e]);
    atomicAdd(&hist[m>>20], 1u);
  }
  __syncthreads();
  {
    u32* src = hist; u32* dst = scratch;
    for (int off=1; off<4096; off<<=1){
      for (int i=t;i<4096;i+=1024){
        u32 v = src[i];
        if (i+off < 4096) v += src[i+off];
        dst[i] = v;
      }
      __syncthreads();
      u32* tmp = src; src = dst; dst = tmp;
    }
    for (int i=t;i<4096;i+=1024){
      u32 s0 = src[i];
      if (s0 >= (u32)K && (i==4095 || src[i+1] < (u32)K)) shThr = (u32)i;
    }
    if (t==0) scnt = 0;
    __syncthreads();
  }
  u32 thr = shThr;
  for (int e=t; e<4096; e+=1024) sbuf[e]=0ull;
  __syncthreads();
  for (int e=t; e<N; e+=1024){
    u32 m = fmono(scores[base+e]);
    if ((m>>20) >= thr){
      int p = atomicAdd(&scnt, 1);
      if (p < 4096) sbuf[p] = ((u64)m << 32) | (u32)(~(u32)e);
    }
  }
  __syncthreads();
  for (int k=2;k<=4096;k<<=1)
    for (int j=k>>1;j>0;j>>=1){
      for (int i=t;i<4096;i+=1024){
        int ixj = i^j;
        if (ixj > i){
          u64 x = sbuf[i], y = sbuf[ixj];
          bool up = ((i & k) == 0);
          bool swp = up ? (x<y) : (x>y);
          if (swp){ sbuf[i]=y; sbuf[ixj]=x; }
        }
      }
      __syncthreads();
    }
  if (t<K){
    u64 key = sbuf[t];
    u32 idx = ~((u32)key);
    top_idx[lvl*1000+t] = idx;
    top_s[lvl*1000+t]   = scores[base + (int)idx];
  }
}

// ---------------- decode (fused) + global stable argsort over 4000 via bitonic-4096
__global__ __launch_bounds__(1024) void sort_k(const u32* __restrict__ top_idx, const float* __restrict__ top_s,
  const float* __restrict__ deltas,
  float* __restrict__ cat_sc, float4* __restrict__ cat_bx,
  float* __restrict__ scores_s, float4* __restrict__ boxes_s, float4* __restrict__ obox)
{
  int t = threadIdx.x;
  for (int e=t; e<4000; e+=1024){
    int lvl = e/1000;
    u32 idx = top_idx[e];
    float score = top_s[e];
    int W = g_H[lvl];
    int strd = g_strideI[lvl];
    float size = g_size[lvl];
    int a = (int)(idx % 3u); int pix = (int)(idx / 3u);
    int px = pix % W, py = pix / W;
    double area = (double)size*(double)size;
    double ar = (a==0)?0.5:((a==1)?1.0:2.0);
    double wd = sqrt(area/ar);
    double hd = ar*wd;
    float bx1 = (float)(-wd*0.5), by1 = (float)(-hd*0.5), bx2=(float)(wd*0.5), by2=(float)(hd*0.5);
    float sx = ((float)px + 0.5f)*(float)strd;
    float sy = ((float)py + 0.5f)*(float)strd;
    float ax1 = sx+bx1, ay1=sy+by1, ax2=sx+bx2, ay2=sy+by2;
    float w = fmaxf(ax2-ax1, 1e-6f), h = fmaxf(ay2-ay1, 1e-6f);
    float cx = ax1 + 0.5f*w, cy = ay1 + 0.5f*h;
    const float* d = &deltas[(size_t)(g_cofs[lvl] + (int)idx)*4];
    float dx = d[0], dy = d[1];
    float dwv = fminf(d[2], 4.135166556742356f);
    float dhv = fminf(d[3], 4.135166556742356f);
    float pcx = cx + dx*w, pcy = cy + dy*h;
    float pw = w*expf(dwv), ph = h*expf(dhv);
    float x1 = pcx - 0.5f*pw, y1 = pcy - 0.5f*ph, x2 = pcx + 0.5f*pw, y2 = pcy + 0.5f*ph;
    x1 = fminf(fmaxf(x1,0.f),639.f); y1 = fminf(fmaxf(y1,0.f),639.f);
    x2 = fminf(fmaxf(x2,0.f),639.f); y2 = fminf(fmaxf(y2,0.f),639.f);
    bool valid = ((x2-x1) >= 4.f) && ((y2-y1) >= 4.f);
    cat_bx[e] = make_float4(x1,y1,x2,y2);
    cat_sc[e] = valid ? score : -1e30f;
  }
  __syncthreads();
  __shared__ u64 s[4096];
  for (int i=t;i<4096;i+=1024){
    u64 key = 0;
    if (i<4000) key = ((u64)fmono(cat_sc[i])<<32) | (u32)(~(u32)i);
    s[i]=key;
  }
  __syncthreads();
  for (int k=2;k<=4096;k<<=1)
    for (int j=k>>1;j>0;j>>=1){
      for (int i=t;i<4096;i+=1024){
        int ixj=i^j;
        if (ixj>i){
          u64 x=s[i], y=s[ixj];
          bool up = ((i&k)==0);
          bool swp = up ? (x<y):(x>y);
          if (swp){ s[i]=y; s[ixj]=x; }
        }
      }
      __syncthreads();
    }
  for (int r=t;r<4000;r+=1024){
    u32 o = ~((u32)s[r]);
    float4 b = cat_bx[o];
    scores_s[r] = cat_sc[o];
    boxes_s[r] = b;
    float off = (float)(o/1000u) * 1282.0f;
    obox[r] = make_float4(b.x+off, b.y+off, b.z+off, b.w+off);
  }
}

// ---------------- pairwise IoU suppression bitmask
__global__ __launch_bounds__(256) void iou_k(const float4* __restrict__ obox, u64* __restrict__ mask)
{
  int w = threadIdx.x;
  int i = blockIdx.x*4 + threadIdx.y;
  if (i >= 4000 || w >= 63) return;
  float4 bi = obox[i];
  float ai = fmaxf(bi.z-bi.x,0.f)*fmaxf(bi.w-bi.y,0.f);
  u64 bits=0;
  int c0=w*64;
  for (int l=0;l<64;l++){
    int c=c0+l;
    if (c>=4000) break;
    if (c<=i) continue;
    float4 bc = obox[c];
    float ac = fmaxf(bc.z-bc.x,0.f)*fmaxf(bc.w-bc.y,0.f);
    float ltx = fmaxf(bi.x, bc.x), lty = fmaxf(bi.y, bc.y);
    float rbx = fminf(bi.z, bc.z), rby = fminf(bi.w, bc.w);
    float wx = fmaxf(rbx-ltx,0.f), wy = fmaxf(rby-lty,0.f);
    float inter = wx*wy;
    float uni = fmaxf(ai+ac-inter, 1e-6f);
    if (inter/uni > 0.7f) bits |= (1ull<<l);
  }
  mask[(size_t)i*63 + w] = bits;
}

// ---------------- NMS scan: group-at-a-time (2 shfl / 64 boxes) + parallel top-150 extraction
__global__ __launch_bounds__(64) void nms_scan_k(const u64* __restrict__ mask,
   const float* __restrict__ scores_s, const float4* __restrict__ boxes_s, float4* __restrict__ props)
{
  int lane = threadIdx.x;
  bool act = lane < 63;
  const u64* mrow = mask + lane;
  u64 removed = 0;

  const int NG = 63;
  u64 bufA[64], bufB[64];
  #pragma unroll
  for (int j=0;j<64;j++){
    int i = j;
    bufA[j] = (act && i < 4000) ? mrow[(size_t)i*63] : 0ull;
  }

  for (int g=0; g<NG; g+=2){
    if (g+1 < NG){
      #pragma unroll
      for (int j=0;j<64;j++){
        int i = (g+1)*64 + j;
        bufB[j] = (act && i < 4000) ? mrow[(size_t)i*63] : 0ull;
      }
    }
    {
      u64 rm = removed, kb = 0;
      #pragma unroll
      for (int j=0;j<64;j++){
        u64 bit = 1ull<<j;
        bool keep = ((rm & bit) == 0ull);
        if (keep){ kb |= bit; rm |= bufA[j]; }
      }
      kb = __shfl(kb, g, 64);
      #pragma unroll
      for (int j=0;j<64;j++){
        if ((kb >> j) & 1ull) removed |= bufA[j];
      }
    }
    if (g+2 < NG){
      #pragma unroll
      for (int j=0;j<64;j++){
        int i = (g+2)*64 + j;
        bufA[j] = (act && i < 4000) ? mrow[(size_t)i*63] : 0ull;
      }
    }
    if (g+1 < NG){
      u64 rm = removed, kb = 0;
      #pragma unroll
      for (int j=0;j<64;j++){
        u64 bit = 1ull<<j;
        bool keep = ((rm & bit) == 0ull);
        if (keep){ kb |= bit; rm |= bufB[j]; }
      }
      kb = __shfl(kb, g+1, 64);
      #pragma unroll
      for (int j=0;j<64;j++){
        if ((kb >> j) & 1ull) removed |= bufB[j];
      }
    }
  }

  u64 keepbits = ~removed;
  u64 selbits = 0;
  if (act){
    #pragma unroll
    for (int j=0;j<64;j++){
      int i = lane*64 + j;
      if (i < 4000 && ((keepbits>>j)&1ull) && scores_s[i] > -1e29f) selbits |= (1ull<<j);
    }
  }
  u64 validbits = 0;
  if (act){
    int nvalid = 4000 - lane*64;
    if (nvalid >= 64) validbits = ~0ull;
    else if (nvalid > 0) validbits = (1ull<<nvalid) - 1ull;
  }
  u64 nonbits = (~selbits) & validbits;

  int cntSel = __popcll(selbits);
  int incS = cntSel;
  #pragma unroll
  for (int off2=1; off2<64; off2<<=1){ int v = __shfl_up(incS, off2, 64); if (lane>=off2) incS += v; }
  int exSel = incS - cntSel;
  int totalSel = __shfl(incS, 63, 64);
  int cnt = totalSel < 150 ? totalSel : 150;

  int cntNon = __popcll(nonbits);
  int incN = cntNon;
  #pragma unroll
  for (int off2=1; off2<64; off2<<=1){ int v = __shfl_up(incN, off2, 64); if (lane>=off2) incN += v; }
  int exNon = incN - cntNon;

  if (act){
    int r = exSel;
    #pragma unroll
    for (int j=0;j<64;j++){
      if ((selbits>>j)&1ull){
        if (r < 150) props[r] = boxes_s[lane*64 + j];
        r++;
      }
    }
    int r2 = cnt + exNon;
    #pragma unroll
    for (int j=0;j<64;j++){
      if ((nonbits>>j)&1ull){
        if (r2 < 150) props[r2] = boxes_s[lane*64 + j];
        r2++;
      }
    }
  }
}

// ---------------- ROI align; x0[roi][c*49+p]
__global__ __launch_bounds__(256) void roi_k(const float* __restrict__ p2, const float* __restrict__ p3,
  const float* __restrict__ p4, const float* __restrict__ p5, const float4* __restrict__ props, float* __restrict__ x0)
{
  int roi = blockIdx.y, p = blockIdx.x, c = threadIdx.x;
  float4 b = props[roi];
  float pw = fmaxf(b.z-b.x, 0.f), ph = fmaxf(b.w-b.y, 0.f);
  float kf = floorf(4.f + log2f(sqrtf(pw*ph)/224.f + 1e-6f));
  kf = fminf(fmaxf(kf, 2.f), 5.f);
  int lvl = (int)kf - 2;
  const float* f = (lvl==0)?p2:((lvl==1)?p3:((lvl==2)?p4:p5));
  int H = g_H[lvl]; int HW = H*H;
  float scale = 1.f/(float)g_strideI[lvl];
  float x1 = b.x*scale, y1 = b.y*scale, x2 = b.z*scale, y2 = b.w*scale;
  float bw = fmaxf(x2-x1, 1.f), bh = fmaxf(y2-y1, 1.f);
  int py = p/7, px = p%7;
  float gx = ((float)px + 0.5f)/7.f;
  float gy = ((float)py + 0.5f)/7.f;
  float X = x1 + gx*bw;
  float Y = y1 + gy*bh;
  float x0f = floorf(X), y0f = floorf(Y);
  float lx = X - x0f, ly = Y - y0f;
  int xi0 = (int)fminf(fmaxf(x0f,0.f),(float)(H-1));
  int xi1 = (int)fminf(fmaxf(x0f+1.f,0.f),(float)(H-1));
  int yi0 = (int)fminf(fmaxf(y0f,0.f),(float)(H-1));
  int yi1 = (int)fminf(fmaxf(y0f+1.f,0.f),(float)(H-1));
  float v00 = f[(size_t)c*HW + yi0*H + xi0];
  float v01 = f[(size_t)c*HW + yi0*H + xi1];
  float v10 = f[(size_t)c*HW + yi1*H + xi0];
  float v11 = f[(size_t)c*HW + yi1*H + xi1];
  float val = v00*(1.f-ly)*(1.f-lx) + v01*(1.f-ly)*lx + v10*ly*(1.f-lx) + v11*ly*lx;
  x0[(size_t)roi*12544 + c*49 + p] = val;
}

// ---------------- split-K partial GEMM: partial[z][M][N] += X[M][Kchunk] @ Wt[N][Kchunk]^T
__global__ __launch_bounds__(256) void fc_split_k(const float* __restrict__ X, const float* __restrict__ Wt,
  float* __restrict__ partial, int M, int N, int K, int KS)
{
  __shared__ float sx[32][33];
  __shared__ float sw[32][64];
  int t = threadIdx.x;
  int tn = t & 15, tm = t >> 4;
  int nb = blockIdx.x, mb = blockIdx.y, zb = blockIdx.z;
  int row0 = mb*32 + tm*2, col0 = nb*64 + tn*4;
  int kbeg = zb*KS, kend = kbeg + KS;
  float acc[2][4] = {{0,0,0,0},{0,0,0,0}};
  int wn = t & 63, kg = t >> 6;
  for (int k0=kbeg;k0<kend;k0+=32){
    for (int e=t;e<1024;e+=256){
      int m=e>>5, kk=e&31;
      int row=mb*32+m;
      sx[m][kk] = (row<M)? X[(size_t)row*K + k0+kk] : 0.f;
    }
    int co = nb*64+wn;
    if (co<N){
      const float* wp = &Wt[(size_t)co*K + k0 + kg*8];
      float4 va = *(const float4*)wp;
      float4 vb = *(const float4*)(wp+4);
      sw[kg*8+0][wn]=va.x; sw[kg*8+1][wn]=va.y; sw[kg*8+2][wn]=va.z; sw[kg*8+3][wn]=va.w;
      sw[kg*8+4][wn]=vb.x; sw[kg*8+5][wn]=vb.y; sw[kg*8+6][wn]=vb.z; sw[kg*8+7][wn]=vb.w;
    } else {
      #pragma unroll
      for (int j=0;j<8;j++) sw[kg*8+j][wn]=0.f;
    }
    __syncthreads();
    #pragma unroll 8
    for (int kk=0;kk<32;kk++){
      float xa = sx[tm*2+0][kk], xb = sx[tm*2+1][kk];
      float4 wv = *(const float4*)&sw[kk][tn*4];
      acc[0][0]=fmaf(xa,wv.x,acc[0][0]); acc[0][1]=fmaf(xa,wv.y,acc[0][1]);
      acc[0][2]=fmaf(xa,wv.z,acc[0][2]); acc[0][3]=fmaf(xa,wv.w,acc[0][3]);
      acc[1][0]=fmaf(xb,wv.x,acc[1][0]); acc[1][1]=fmaf(xb,wv.y,acc[1][1]);
      acc[1][2]=fmaf(xb,wv.z,acc[1][2]); acc[1][3]=fmaf(xb,wv.w,acc[1][3]);
    }
    __syncthreads();
  }
  for (int dm=0;dm<2;dm++){
    int row=row0+dm; if (row>=M) continue;
    for (int dn=0;dn<4;dn++){
      int col=col0+dn; if (col>=N) continue;
      partial[((size_t)zb*M + row)*N + col] = acc[dm][dn];
    }
  }
}

// ---------------- split-K reduce: Y = act(sum_z partial[z] + bias)
__global__ __launch_bounds__(256) void fc_reduce_k(const float* __restrict__ partial, const float* __restrict__ bias,
  float* __restrict__ Y, int M, int N, int S, int dorelu)
{
  int idx = blockIdx.x*256 + threadIdx.x;
  if (idx >= M*N) return;
  int col = idx % N;
  float v = bias[col];
  size_t stride = (size_t)M*N;
  for (int s=0;s<S;s++) v += partial[s*stride + idx];
  if (dorelu) v = fmaxf(v, 0.f);
  Y[idx] = v;
}

extern "C" void kernel_launch(void* const* d_in, const int* in_sizes, int n_in,
                              void* d_out, int out_size, void* d_ws, size_t ws_size,
                              hipStream_t stream)
{
  (void)in_sizes; (void)n_in; (void)out_size; (void)ws_size;
  const float* p[4] = {(const float*)d_in[0], (const float*)d_in[1], (const float*)d_in[2], (const float*)d_in[3]};
  const float* rpn_w = (const float*)d_in[4];
  const float* rpn_b = (const float*)d_in[5];
  const float* obj_w = (const float*)d_in[6];
  const float* obj_b = (const float*)d_in[7];
  const float* del_w = (const float*)d_in[8];
  const float* del_b = (const float*)d_in[9];
  const float* fc1_w = (const float*)d_in[10];
  const float* fc1_b = (const float*)d_in[11];
  const float* fc2_w = (const float*)d_in[12];
  const float* fc2_b = (const float*)d_in[13];
  const float* cls_w = (const float*)d_in[14];
  const float* cls_b = (const float*)d_in[15];
  const float* bbox_w= (const float*)d_in[16];
  const float* bbox_b= (const float*)d_in[17];

  char* ws = (char*)d_ws;
  size_t off = 0;
  auto alloc = [&](size_t bytes){ size_t o = off; off += (bytes + 255) & ~(size_t)255; return o; };
  float*  wT1      = (float*)(ws + alloc(589824ull*4));
  float*  hid      = (float*)(ws + alloc(34000ull*256*4));
  float*  scores   = (float*)(ws + alloc(102000ull*4));
  float*  deltas   = (float*)(ws + alloc(102000ull*16));
  float*  top_s    = (float*)(ws + alloc(4000ull*4));
  u32*    top_idx  = (u32*)  (ws + alloc(4000ull*4));
  float*  cat_sc   = (float*)(ws + alloc(4000ull*4));
  float4* cat_bx   = (float4*)(ws + alloc(4000ull*16));
  float*  scores_s = (float*)(ws + alloc(4000ull*4));
  float4* boxes_s  = (float4*)(ws + alloc(4000ull*16));
  float4* obox     = (float4*)(ws + alloc(4000ull*16));
  u64*    mask     = (u64*)  (ws + alloc(4000ull*63*8));
  float4* props    = (float4*)(ws + alloc(150ull*16));
  float*  x0       = (float*)(ws + alloc(150ull*12544*4));
  float*  x1       = (float*)(ws + alloc(150ull*1024*4));
  float*  x2       = (float*)(ws + alloc(150ull*1024*4));
  float*  wcat     = (float*)(ws + alloc(105ull*1024*4));
  float*  bcat     = (float*)(ws + alloc(105ull*4));
  float*  convp    = (float*)(ws + alloc(36864000ull*4));
  float*  partial  = hid;

  hipLaunchKernelGGL(prep_k, dim3(996), dim3(256), 0, stream,
                     rpn_w, wT1, cls_w, cls_b, bbox_w, bbox_b, wcat, bcat);

  hipLaunchKernelGGL(rpn_conv_all_k, dim3(2416), dim3(256), 0, stream,
                     p[0], p[1], p[2], p[3], wT1, convp);

  hipLaunchKernelGGL(rpn_heads_k, dim3((34000+63)/64), dim3(256), 0, stream,
                     convp, rpn_b, obj_w, obj_b, del_w, del_b, scores, deltas);
  hipLaunchKernelGGL(topk_k, dim3(4), dim3(1024), 0, stream, scores, top_s, top_idx);
  hipLaunchKernelGGL(sort_k, dim3(1), dim3(1024), 0, stream, top_idx, top_s, deltas,
                     cat_sc, cat_bx, scores_s, boxes_s, obox);
  hipLaunchKernelGGL(iou_k, dim3(1000), dim3(64,4), 0, stream, obox, mask);
  hipLaunchKernelGGL(nms_scan_k, dim3(1), dim3(64), 0, stream, mask, scores_s, boxes_s, props);
  hipLaunchKernelGGL(roi_k, dim3(49,150), dim3(256), 0, stream, p[0],p[1],p[2],p[3], props, x0);

  hipLaunchKernelGGL(fc_split_k, dim3(16,5,28), dim3(256), 0, stream, x0, fc1_w, partial, 150, 1024, 12544, 448);
  hipLaunchKernelGGL(fc_reduce_k, dim3((150*1024+255)/256), dim3(256), 0, stream, partial, fc1_b, x1, 150, 1024, 28, 1);
  hipLaunchKernelGGL(fc_split_k, dim3(16,5,8), dim3(256), 0, stream, x1, fc2_w, partial, 150, 1024, 1024, 128);
  hipLaunchKernelGGL(fc_reduce_k, dim3((150*1024+255)/256), dim3(256), 0, stream, partial, fc2_b, x2, 150, 1024, 8, 1);
  hipLaunchKernelGGL(fc_split_k, dim3(2,5,8), dim3(256), 0, stream, x2, wcat, partial, 150, 105, 1024, 128);
  hipLaunchKernelGGL(fc_reduce_k, dim3((150*105+255)/256), dim3(256), 0, stream, partial, bcat, (float*)d_out, 150, 105, 8, 0);
}

// Round 24
// 1171.940 us; speedup vs baseline: 4.7927x; 4.7927x over previous
//
#include <hip/hip_runtime.h>
#include <cstdint>

typedef unsigned long long u64;
typedef unsigned int u32;

__device__ inline u32 fmono(float f){ u32 u = __float_as_uint(f); u32 m = (u & 0x80000000u) ? 0xFFFFFFFFu : 0x80000000u; return u ^ m; }

__device__ const int    g_H[4]       = {160, 80, 40, 20};
__device__ const int    g_strideI[4] = {4, 8, 16, 32};
__device__ const float  g_size[4]    = {32.f, 64.f, 128.f, 256.f};
__device__ const int    g_cofs[4]    = {0, 76800, 96000, 100800};
__device__ const int    g_cnt[4]     = {76800, 19200, 4800, 1200};
__device__ const int    c_blkBase[5] = {0, 1600, 2000, 2288, 2416};
__device__ const int    c_S[4]       = {4, 4, 8, 8};
__device__ const int    c_pofs[4]    = {0, 25600, 32000, 33600};
__device__ const size_t c_partofs[4] = {0, 26214400, 32768000, 36044800};

// ---------------- prep: weight transpose (blocks 0..575) + head-weight concat (blocks 576..995)
__global__ __launch_bounds__(256) void prep_k(const float* __restrict__ w, float* __restrict__ wT,
  const float* __restrict__ cls_w, const float* __restrict__ cls_b,
  const float* __restrict__ bbox_w, const float* __restrict__ bbox_b,
  float* __restrict__ wcat, float* __restrict__ bcat)
{
  int b = blockIdx.x;
  if (b < 576){
    __shared__ float tile[32][33];
    int tx = threadIdx.x & 31, ty = threadIdx.x >> 5;
    int row0 = (b % 72)*32, co0 = (b / 72)*32;
    #pragma unroll
    for (int r=0;r<4;r++){
      int co = co0 + ty + r*8;
      tile[ty+r*8][tx] = w[(size_t)co*2304 + row0 + tx];
    }
    __syncthreads();
    #pragma unroll
    for (int r=0;r<4;r++){
      int row = row0 + ty + r*8;
      wT[(size_t)row*256 + co0 + tx] = tile[tx][ty+r*8];
    }
  } else {
    int t = (b-576)*256 + threadIdx.x;
    if (t < 105*1024){ int o = t >> 10, k = t & 1023; wcat[t] = (o < 21) ? cls_w[o*1024+k] : bbox_w[(o-21)*1024+k]; }
    if (t < 105) bcat[t] = (t < 21) ? cls_b[t] : bbox_b[t-21];
  }
}

// ---------------- fused 3x3 conv over ALL levels (single-buffer; R20/R22-proven schedule).
#define KC 4
__global__ __launch_bounds__(256) void rpn_conv_all_k(
    const float* __restrict__ p0, const float* __restrict__ p1,
    const float* __restrict__ p2f, const float* __restrict__ p3f,
    const float* __restrict__ wT, float* __restrict__ convp)
{
  int bid = blockIdx.x;
  int lvl = (bid >= c_blkBase[1]) + (bid >= c_blkBase[2]) + (bid >= c_blkBase[3]);
  int local = bid - c_blkBase[lvl];
  int nz  = c_S[lvl];
  int H = g_H[lvl], W = H;
  const float* in = (lvl==0)?p0:((lvl==1)?p1:((lvl==2)?p2f:p3f));
  float* part = convp + c_partofs[lvl];
  int zb   = local % nz;
  int cb   = (local / nz) & 3;
  int tile = local / (nz*4);

  int tilesX = (W + 15) >> 4;
  int tr0 = (tile / tilesX) * 16;
  int tc0 = (tile % tilesX) * 16;
  int ciPer = 256 / nz;
  int ciBeg = zb * ciPer;
  int t   = threadIdx.x;
  int tco = t & 15, tp = t >> 4;
  int pr = (tp >> 2) * 4, pc = (tp & 3) * 4;
  int HW = H*W;

  __shared__ float sIn[KC][18][20];
  __shared__ float sW[KC*9][64];

  float* sInF = &sIn[0][0][0];
  float* sWF  = &sW[0][0];

  int   iOff[6]; int iLds[6]; bool iOk[6];
  #pragma unroll
  for (int s=0;s<6;s++){
    int e = t + s*256;
    bool a = (s<5) || (t < (KC*324 - 5*256));
    int ee = a ? e : 0;
    int c = ee/324, r2 = ee%324, row = r2/18, col = r2%18;
    int gy = tr0+row-1, gx = tc0+col-1;
    bool ok = a && ((unsigned)gy < (unsigned)H) && ((unsigned)gx < (unsigned)W);
    iOff[s] = c*HW + gy*W + gx;
    iLds[s] = c*360 + row*20 + col;
    iOk[s]  = ok;
  }
  bool iAct5 = (t < (KC*324 - 5*256));
  int wOff[3]; int wLds[3];
  #pragma unroll
  for (int s=0;s<3;s++){
    int e4 = t + s*256;
    bool a = (s<2) || (t < (KC*9*16 - 2*256));
    int ee = a ? e4 : 0;
    int row = ee>>4, c4 = (ee&15)<<2;
    wOff[s] = row*256 + cb*64 + c4;
    wLds[s] = row*64 + c4;
  }
  bool wAct2 = (t < (KC*9*16 - 2*256));

  float acc[4][16];
  #pragma unroll
  for (int o=0;o<4;o++)
    #pragma unroll
    for (int p=0;p<16;p++) acc[o][p]=0.f;

  float  ri0,ri1,ri2,ri3,ri4,ri5;
  float4 rw0,rw1,rw2;

  {
    const float* inb = in + (size_t)ciBeg*HW;
    const float* wb  = wT + (size_t)ciBeg*2304;
    ri0 = iOk[0] ? inb[iOff[0]] : 0.f;
    ri1 = iOk[1] ? inb[iOff[1]] : 0.f;
    ri2 = iOk[2] ? inb[iOff[2]] : 0.f;
    ri3 = iOk[3] ? inb[iOff[3]] : 0.f;
    ri4 = iOk[4] ? inb[iOff[4]] : 0.f;
    ri5 = iOk[5] ? inb[iOff[5]] : 0.f;
    rw0 = *(const float4*)&wb[wOff[0]];
    rw1 = *(const float4*)&wb[wOff[1]];
    if (wAct2) rw2 = *(const float4*)&wb[wOff[2]];
  }

  int ciEnd = ciBeg + ciPer;
  for (int ci0=ciBeg; ci0<ciEnd; ci0+=KC){
    sInF[iLds[0]] = ri0; sInF[iLds[1]] = ri1; sInF[iLds[2]] = ri2;
    sInF[iLds[3]] = ri3; sInF[iLds[4]] = ri4;
    if (iAct5) sInF[iLds[5]] = ri5;
    *(float4*)&sWF[wLds[0]] = rw0;
    *(float4*)&sWF[wLds[1]] = rw1;
    if (wAct2) *(float4*)&sWF[wLds[2]] = rw2;
    __syncthreads();

    if (ci0 + KC < ciEnd){
      const float* inb = in + (size_t)(ci0+KC)*HW;
      const float* wb  = wT + (size_t)(ci0+KC)*2304;
      ri0 = iOk[0] ? inb[iOff[0]] : 0.f;
      ri1 = iOk[1] ? inb[iOff[1]] : 0.f;
      ri2 = iOk[2] ? inb[iOff[2]] : 0.f;
      ri3 = iOk[3] ? inb[iOff[3]] : 0.f;
      ri4 = iOk[4] ? inb[iOff[4]] : 0.f;
      ri5 = iOk[5] ? inb[iOff[5]] : 0.f;
      rw0 = *(const float4*)&wb[wOff[0]];
      rw1 = *(const float4*)&wb[wOff[1]];
      if (wAct2) rw2 = *(const float4*)&wb[wOff[2]];
    }

    #pragma unroll
    for (int c=0;c<KC;c++){
      float rin[6][6];
      #pragma unroll
      for (int rr=0;rr<6;rr++){
        float4 a = *(const float4*)&sIn[c][pr+rr][pc];
        float2 b = *(const float2*)&sIn[c][pr+rr][pc+4];
        rin[rr][0]=a.x; rin[rr][1]=a.y; rin[rr][2]=a.z; rin[rr][3]=a.w;
        rin[rr][4]=b.x; rin[rr][5]=b.y;
      }
      #pragma unroll
      for (int k=0;k<9;k++){
        int ky=k/3, kx=k%3;
        float4 w0 = *(const float4*)&sW[c*9+k][tco*4];
        float wv[4] = {w0.x,w0.y,w0.z,w0.w};
        #pragma unroll
        for (int dr=0;dr<4;dr++)
          #pragma unroll
          for (int dc=0;dc<4;dc++){
            float iv = rin[dr+ky][dc+kx];
            int p = dr*4+dc;
            #pragma unroll
            for (int o=0;o<4;o++) acc[o][p] = fmaf(wv[o], iv, acc[o][p]);
          }
      }
    }
    __syncthreads();
  }

  int coBase = cb*64 + tco*4;
  float* pb = part + (size_t)zb*HW*256;
  #pragma unroll
  for (int dr=0;dr<4;dr++){
    int gy = tr0+pr+dr; if (gy>=H) continue;
    #pragma unroll
    for (int dc=0;dc<4;dc++){
      int gx = tc0+pc+dc; if (gx>=W) continue;
      int p = dr*4+dc;
      *(float4*)&pb[(size_t)(gy*W+gx)*256 + coBase] = make_float4(acc[0][p],acc[1][p],acc[2][p],acc[3][p]);
    }
  }
}

// ---------------- 1x1 heads fused with conv-reduce: reads convp directly.
__global__ __launch_bounds__(256) void rpn_heads_k(
  const float* __restrict__ convp, const float* __restrict__ cbias,
  const float* __restrict__ ow, const float* __restrict__ ob,
  const float* __restrict__ dw, const float* __restrict__ db,
  float* __restrict__ scores, float* __restrict__ deltas)
{
  __shared__ float sw[15][256];
  int t = threadIdx.x;
  for (int e=t; e<15*256; e+=256){ int o=e>>8, k=e&255; sw[o][k] = (o<3)? ow[o*256+k] : dw[(o-3)*256+k]; }
  __syncthreads();
  int wv = t>>6, lane = t&63;
  float4 bv = *(const float4*)&cbias[lane*4];
  #pragma unroll
  for (int i=0;i<16;i++){
    int gpx = blockIdx.x*64 + wv*16 + i;
    if (gpx >= 34000) return;
    int lvl = (gpx >= 25600) + (gpx >= 32000) + (gpx >= 33600);
    int S = c_S[lvl];
    size_t stride = (size_t)g_H[lvl]*g_H[lvl]*256;
    const float* pb = convp + c_partofs[lvl] + (size_t)(gpx - c_pofs[lvl])*256 + lane*4;
    float vx=0.f, vy=0.f, vz=0.f, vw=0.f;
    for (int s=0;s<S;s++){
      float4 q = *(const float4*)(pb + (size_t)s*stride);
      vx += q.x; vy += q.y; vz += q.z; vw += q.w;
    }
    vx += bv.x; vy += bv.y; vz += bv.z; vw += bv.w;
    vx = vx>0.f?vx:0.f; vy = vy>0.f?vy:0.f; vz = vz>0.f?vz:0.f; vw = vw>0.f?vw:0.f;
    float a[15];
    #pragma unroll
    for (int o=0;o<15;o++){
      const float* w = &sw[o][lane*4];
      a[o] = w[0]*vx + w[1]*vy + w[2]*vz + w[3]*vw;
    }
    #pragma unroll
    for (int off=32; off; off>>=1)
      #pragma unroll
      for (int o=0;o<15;o++) a[o] += __shfl_xor(a[o], off, 64);
    if (lane==0){
      for (int q=0;q<3;q++) scores[gpx*3+q] = a[q] + ob[q];
      for (int q=0;q<3;q++)
        for (int j=0;j<4;j++)
          deltas[(size_t)(gpx*3+q)*4 + j] = a[3+q*4+j] + db[q*4+j];
    }
  }
}

// ---------------- exact per-level top-1000: histogram + parallel suffix-scan threshold + collect + bitonic
__global__ __launch_bounds__(1024) void topk_k(
  const float* __restrict__ scores, float* __restrict__ top_s, u32* __restrict__ top_idx)
{
  int lvl = blockIdx.x;
  int base = g_cofs[lvl], N = g_cnt[lvl];
  const int K = 1000;
  __shared__ u32 hist[4096];
  __shared__ u64 sbuf[4096];
  __shared__ u32 shThr; __shared__ int scnt;
  u32* scratch = (u32*)sbuf;
  int t = threadIdx.x;
  for (int e=t; e<4096; e+=1024) hist[e]=0;
  __syncthreads();
  for (int e=t; e<N; e+=1024){
    u32 m = fmono(scores[base+e]);
    atomicAdd(&hist[m>>20], 1u);
  }
  __syncthreads();
  {
    u32* src = hist; u32* dst = scratch;
    for (int off=1; off<4096; off<<=1){
      for (int i=t;i<4096;i+=1024){
        u32 v = src[i];
        if (i+off < 4096) v += src[i+off];
        dst[i] = v;
      }
      __syncthreads();
      u32* tmp = src; src = dst; dst = tmp;
    }
    for (int i=t;i<4096;i+=1024){
      u32 s0 = src[i];
      if (s0 >= (u32)K && (i==4095 || src[i+1] < (u32)K)) shThr = (u32)i;
    }
    if (t==0) scnt = 0;
    __syncthreads();
  }
  u32 thr = shThr;
  for (int e=t; e<4096; e+=1024) sbuf[e]=0ull;
  __syncthreads();
  for (int e=t; e<N; e+=1024){
    u32 m = fmono(scores[base+e]);
    if ((m>>20) >= thr){
      int p = atomicAdd(&scnt, 1);
      if (p < 4096) sbuf[p] = ((u64)m << 32) | (u32)(~(u32)e);
    }
  }
  __syncthreads();
  for (int k=2;k<=4096;k<<=1)
    for (int j=k>>1;j>0;j>>=1){
      for (int i=t;i<4096;i+=1024){
        int ixj = i^j;
        if (ixj > i){
          u64 x = sbuf[i], y = sbuf[ixj];
          bool up = ((i & k) == 0);
          bool swp = up ? (x<y) : (x>y);
          if (swp){ sbuf[i]=y; sbuf[ixj]=x; }
        }
      }
      __syncthreads();
    }
  if (t<K){
    u64 key = sbuf[t];
    u32 idx = ~((u32)key);
    top_idx[lvl*1000+t] = idx;
    top_s[lvl*1000+t]   = scores[base + (int)idx];
  }
}

// ---------------- decode (fused) + global stable argsort over 4000 via bitonic-4096
__global__ __launch_bounds__(1024) void sort_k(const u32* __restrict__ top_idx, const float* __restrict__ top_s,
  const float* __restrict__ deltas,
  float* __restrict__ cat_sc, float4* __restrict__ cat_bx,
  float* __restrict__ scores_s, float4* __restrict__ boxes_s, float4* __restrict__ obox)
{
  int t = threadIdx.x;
  for (int e=t; e<4000; e+=1024){
    int lvl = e/1000;
    u32 idx = top_idx[e];
    float score = top_s[e];
    int W = g_H[lvl];
    int strd = g_strideI[lvl];
    float size = g_size[lvl];
    int a = (int)(idx % 3u); int pix = (int)(idx / 3u);
    int px = pix % W, py = pix / W;
    double area = (double)size*(double)size;
    double ar = (a==0)?0.5:((a==1)?1.0:2.0);
    double wd = sqrt(area/ar);
    double hd = ar*wd;
    float bx1 = (float)(-wd*0.5), by1 = (float)(-hd*0.5), bx2=(float)(wd*0.5), by2=(float)(hd*0.5);
    float sx = ((float)px + 0.5f)*(float)strd;
    float sy = ((float)py + 0.5f)*(float)strd;
    float ax1 = sx+bx1, ay1=sy+by1, ax2=sx+bx2, ay2=sy+by2;
    float w = fmaxf(ax2-ax1, 1e-6f), h = fmaxf(ay2-ay1, 1e-6f);
    float cx = ax1 + 0.5f*w, cy = ay1 + 0.5f*h;
    const float* d = &deltas[(size_t)(g_cofs[lvl] + (int)idx)*4];
    float dx = d[0], dy = d[1];
    float dwv = fminf(d[2], 4.135166556742356f);
    float dhv = fminf(d[3], 4.135166556742356f);
    float pcx = cx + dx*w, pcy = cy + dy*h;
    float pw = w*expf(dwv), ph = h*expf(dhv);
    float x1 = pcx - 0.5f*pw, y1 = pcy - 0.5f*ph, x2 = pcx + 0.5f*pw, y2 = pcy + 0.5f*ph;
    x1 = fminf(fmaxf(x1,0.f),639.f); y1 = fminf(fmaxf(y1,0.f),639.f);
    x2 = fminf(fmaxf(x2,0.f),639.f); y2 = fminf(fmaxf(y2,0.f),639.f);
    bool valid = ((x2-x1) >= 4.f) && ((y2-y1) >= 4.f);
    cat_bx[e] = make_float4(x1,y1,x2,y2);
    cat_sc[e] = valid ? score : -1e30f;
  }
  __syncthreads();
  __shared__ u64 s[4096];
  for (int i=t;i<4096;i+=1024){
    u64 key = 0;
    if (i<4000) key = ((u64)fmono(cat_sc[i])<<32) | (u32)(~(u32)i);
    s[i]=key;
  }
  __syncthreads();
  for (int k=2;k<=4096;k<<=1)
    for (int j=k>>1;j>0;j>>=1){
      for (int i=t;i<4096;i+=1024){
        int ixj=i^j;
        if (ixj>i){
          u64 x=s[i], y=s[ixj];
          bool up = ((i&k)==0);
          bool swp = up ? (x<y):(x>y);
          if (swp){ s[i]=y; s[ixj]=x; }
        }
      }
      __syncthreads();
    }
  for (int r=t;r<4000;r+=1024){
    u32 o = ~((u32)s[r]);
    float4 b = cat_bx[o];
    scores_s[r] = cat_sc[o];
    boxes_s[r] = b;
    float off = (float)(o/1000u) * 1282.0f;
    obox[r] = make_float4(b.x+off, b.y+off, b.z+off, b.w+off);
  }
}

// ---------------- pairwise IoU suppression bitmask
__global__ __launch_bounds__(256) void iou_k(const float4* __restrict__ obox, u64* __restrict__ mask)
{
  int w = threadIdx.x;
  int i = blockIdx.x*4 + threadIdx.y;
  if (i >= 4000 || w >= 63) return;
  float4 bi = obox[i];
  float ai = fmaxf(bi.z-bi.x,0.f)*fmaxf(bi.w-bi.y,0.f);
  u64 bits=0;
  int c0=w*64;
  for (int l=0;l<64;l++){
    int c=c0+l;
    if (c>=4000) break;
    if (c<=i) continue;
    float4 bc = obox[c];
    float ac = fmaxf(bc.z-bc.x,0.f)*fmaxf(bc.w-bc.y,0.f);
    float ltx = fmaxf(bi.x, bc.x), lty = fmaxf(bi.y, bc.y);
    float rbx = fminf(bi.z, bc.z), rby = fminf(bi.w, bc.w);
    float wx = fmaxf(rbx-ltx,0.f), wy = fmaxf(rby-lty,0.f);
    float inter = wx*wy;
    float uni = fmaxf(ai+ac-inter, 1e-6f);
    if (inter/uni > 0.7f) bits |= (1ull<<l);
  }
  mask[(size_t)i*63 + w] = bits;
}

// ---------------- NMS scan: group-at-a-time (2 shfl / 64 boxes) + parallel top-150 extraction
__global__ __launch_bounds__(64) void nms_scan_k(const u64* __restrict__ mask,
   const float* __restrict__ scores_s, const float4* __restrict__ boxes_s, float4* __restrict__ props)
{
  int lane = threadIdx.x;
  bool act = lane < 63;
  const u64* mrow = mask + lane;
  u64 removed = 0;

  const int NG = 63;
  u64 bufA[64], bufB[64];
  #pragma unroll
  for (int j=0;j<64;j++){
    int i = j;
    bufA[j] = (act && i < 4000) ? mrow[(size_t)i*63] : 0ull;
  }

  for (int g=0; g<NG; g+=2){
    if (g+1 < NG){
      #pragma unroll
      for (int j=0;j<64;j++){
        int i = (g+1)*64 + j;
        bufB[j] = (act && i < 4000) ? mrow[(size_t)i*63] : 0ull;
      }
    }
    {
      u64 rm = removed, kb = 0;
      #pragma unroll
      for (int j=0;j<64;j++){
        u64 bit = 1ull<<j;
        bool keep = ((rm & bit) == 0ull);
        if (keep){ kb |= bit; rm |= bufA[j]; }
      }
      kb = __shfl(kb, g, 64);
      #pragma unroll
      for (int j=0;j<64;j++){
        if ((kb >> j) & 1ull) removed |= bufA[j];
      }
    }
    if (g+2 < NG){
      #pragma unroll
      for (int j=0;j<64;j++){
        int i = (g+2)*64 + j;
        bufA[j] = (act && i < 4000) ? mrow[(size_t)i*63] : 0ull;
      }
    }
    if (g+1 < NG){
      u64 rm = removed, kb = 0;
      #pragma unroll
      for (int j=0;j<64;j++){
        u64 bit = 1ull<<j;
        bool keep = ((rm & bit) == 0ull);
        if (keep){ kb |= bit; rm |= bufB[j]; }
      }
      kb = __shfl(kb, g+1, 64);
      #pragma unroll
      for (int j=0;j<64;j++){
        if ((kb >> j) & 1ull) removed |= bufB[j];
      }
    }
  }

  u64 keepbits = ~removed;
  u64 selbits = 0;
  if (act){
    #pragma unroll
    for (int j=0;j<64;j++){
      int i = lane*64 + j;
      if (i < 4000 && ((keepbits>>j)&1ull) && scores_s[i] > -1e29f) selbits |= (1ull<<j);
    }
  }
  u64 validbits = 0;
  if (act){
    int nvalid = 4000 - lane*64;
    if (nvalid >= 64) validbits = ~0ull;
    else if (nvalid > 0) validbits = (1ull<<nvalid) - 1ull;
  }
  u64 nonbits = (~selbits) & validbits;

  int cntSel = __popcll(selbits);
  int incS = cntSel;
  #pragma unroll
  for (int off2=1; off2<64; off2<<=1){ int v = __shfl_up(incS, off2, 64); if (lane>=off2) incS += v; }
  int exSel = incS - cntSel;
  int totalSel = __shfl(incS, 63, 64);
  int cnt = totalSel < 150 ? totalSel : 150;

  int cntNon = __popcll(nonbits);
  int incN = cntNon;
  #pragma unroll
  for (int off2=1; off2<64; off2<<=1){ int v = __shfl_up(incN, off2, 64); if (lane>=off2) incN += v; }
  int exNon = incN - cntNon;

  if (act){
    int r = exSel;
    #pragma unroll
    for (int j=0;j<64;j++){
      if ((selbits>>j)&1ull){
        if (r < 150) props[r] = boxes_s[lane*64 + j];
        r++;
      }
    }
    int r2 = cnt + exNon;
    #pragma unroll
    for (int j=0;j<64;j++){
      if ((nonbits>>j)&1ull){
        if (r2 < 150) props[r2] = boxes_s[lane*64 + j];
        r2++;
      }
    }
  }
}

// ---------------- ROI align; x0[roi][c*49+p]
__global__ __launch_bounds__(256) void roi_k(const float* __restrict__ p2, const float* __restrict__ p3,
  const float* __restrict__ p4, const float* __restrict__ p5, const float4* __restrict__ props, float* __restrict__ x0)
{
  int roi = blockIdx.y, p = blockIdx.x, c = threadIdx.x;
  float4 b = props[roi];
  float pw = fmaxf(b.z-b.x, 0.f), ph = fmaxf(b.w-b.y, 0.f);
  float kf = floorf(4.f + log2f(sqrtf(pw*ph)/224.f + 1e-6f));
  kf = fminf(fmaxf(kf, 2.f), 5.f);
  int lvl = (int)kf - 2;
  const float* f = (lvl==0)?p2:((lvl==1)?p3:((lvl==2)?p4:p5));
  int H = g_H[lvl]; int HW = H*H;
  float scale = 1.f/(float)g_strideI[lvl];
  float x1 = b.x*scale, y1 = b.y*scale, x2 = b.z*scale, y2 = b.w*scale;
  float bw = fmaxf(x2-x1, 1.f), bh = fmaxf(y2-y1, 1.f);
  int py = p/7, px = p%7;
  float gx = ((float)px + 0.5f)/7.f;
  float gy = ((float)py + 0.5f)/7.f;
  float X = x1 + gx*bw;
  float Y = y1 + gy*bh;
  float x0f = floorf(X), y0f = floorf(Y);
  float lx = X - x0f, ly = Y - y0f;
  int xi0 = (int)fminf(fmaxf(x0f,0.f),(float)(H-1));
  int xi1 = (int)fminf(fmaxf(x0f+1.f,0.f),(float)(H-1));
  int yi0 = (int)fminf(fmaxf(y0f,0.f),(float)(H-1));
  int yi1 = (int)fminf(fmaxf(y0f+1.f,0.f),(float)(H-1));
  float v00 = f[(size_t)c*HW + yi0*H + xi0];
  float v01 = f[(size_t)c*HW + yi0*H + xi1];
  float v10 = f[(size_t)c*HW + yi1*H + xi0];
  float v11 = f[(size_t)c*HW + yi1*H + xi1];
  float val = v00*(1.f-ly)*(1.f-lx) + v01*(1.f-ly)*lx + v10*ly*(1.f-lx) + v11*ly*lx;
  x0[(size_t)roi*12544 + c*49 + p] = val;
}

// ---------------- split-K partial GEMM: partial[z][M][N] += X[M][Kchunk] @ Wt[N][Kchunk]^T
__global__ __launch_bounds__(256) void fc_split_k(const float* __restrict__ X, const float* __restrict__ Wt,
  float* __restrict__ partial, int M, int N, int K, int KS)
{
  __shared__ float sx[32][33];
  __shared__ float sw[32][64];
  int t = threadIdx.x;
  int tn = t & 15, tm = t >> 4;
  int nb = blockIdx.x, mb = blockIdx.y, zb = blockIdx.z;
  int row0 = mb*32 + tm*2, col0 = nb*64 + tn*4;
  int kbeg = zb*KS, kend = kbeg + KS;
  float acc[2][4] = {{0,0,0,0},{0,0,0,0}};
  int wn = t & 63, kg = t >> 6;
  for (int k0=kbeg;k0<kend;k0+=32){
    for (int e=t;e<1024;e+=256){
      int m=e>>5, kk=e&31;
      int row=mb*32+m;
      sx[m][kk] = (row<M)? X[(size_t)row*K + k0+kk] : 0.f;
    }
    int co = nb*64+wn;
    if (co<N){
      const float* wp = &Wt[(size_t)co*K + k0 + kg*8];
      float4 va = *(const float4*)wp;
      float4 vb = *(const float4*)(wp+4);
      sw[kg*8+0][wn]=va.x; sw[kg*8+1][wn]=va.y; sw[kg*8+2][wn]=va.z; sw[kg*8+3][wn]=va.w;
      sw[kg*8+4][wn]=vb.x; sw[kg*8+5][wn]=vb.y; sw[kg*8+6][wn]=vb.z; sw[kg*8+7][wn]=vb.w;
    } else {
      #pragma unroll
      for (int j=0;j<8;j++) sw[kg*8+j][wn]=0.f;
    }
    __syncthreads();
    #pragma unroll 8
    for (int kk=0;kk<32;kk++){
      float xa = sx[tm*2+0][kk], xb = sx[tm*2+1][kk];
      float4 wv = *(const float4*)&sw[kk][tn*4];
      acc[0][0]=fmaf(xa,wv.x,acc[0][0]); acc[0][1]=fmaf(xa,wv.y,acc[0][1]);
      acc[0][2]=fmaf(xa,wv.z,acc[0][2]); acc[0][3]=fmaf(xa,wv.w,acc[0][3]);
      acc[1][0]=fmaf(xb,wv.x,acc[1][0]); acc[1][1]=fmaf(xb,wv.y,acc[1][1]);
      acc[1][2]=fmaf(xb,wv.z,acc[1][2]); acc[1][3]=fmaf(xb,wv.w,acc[1][3]);
    }
    __syncthreads();
  }
  for (int dm=0;dm<2;dm++){
    int row=row0+dm; if (row>=M) continue;
    for (int dn=0;dn<4;dn++){
      int col=col0+dn; if (col>=N) continue;
      partial[((size_t)zb*M + row)*N + col] = acc[dm][dn];
    }
  }
}

// ---------------- split-K reduce: Y = act(sum_z partial[z] + bias)
__global__ __launch_bounds__(256) void fc_reduce_k(const float* __restrict__ partial, const float* __restrict__ bias,
  float* __restrict__ Y, int M, int N, int S, int dorelu)
{
  int idx = blockIdx.x*256 + threadIdx.x;
  if (idx >= M*N) return;
  int col = idx % N;
  float v = bias[col];
  size_t stride = (size_t)M*N;
  for (int s=0;s<S;s++) v += partial[s*stride + idx];
  if (dorelu) v = fmaxf(v, 0.f);
  Y[idx] = v;
}

extern "C" void kernel_launch(void* const* d_in, const int* in_sizes, int n_in,
                              void* d_out, int out_size, void* d_ws, size_t ws_size,
                              hipStream_t stream)
{
  (void)in_sizes; (void)n_in; (void)out_size; (void)ws_size;
  const float* p[4] = {(const float*)d_in[0], (const float*)d_in[1], (const float*)d_in[2], (const float*)d_in[3]};
  const float* rpn_w = (const float*)d_in[4];
  const float* rpn_b = (const float*)d_in[5];
  const float* obj_w = (const float*)d_in[6];
  const float* obj_b = (const float*)d_in[7];
  const float* del_w = (const float*)d_in[8];
  const float* del_b = (const float*)d_in[9];
  const float* fc1_w = (const float*)d_in[10];
  const float* fc1_b = (const float*)d_in[11];
  const float* fc2_w = (const float*)d_in[12];
  const float* fc2_b = (const float*)d_in[13];
  const float* cls_w = (const float*)d_in[14];
  const float* cls_b = (const float*)d_in[15];
  const float* bbox_w= (const float*)d_in[16];
  const float* bbox_b= (const float*)d_in[17];

  char* ws = (char*)d_ws;
  size_t off = 0;
  auto alloc = [&](size_t bytes){ size_t o = off; off += (bytes + 255) & ~(size_t)255; return o; };
  float*  wT1      = (float*)(ws + alloc(589824ull*4));
  float*  hid      = (float*)(ws + alloc(34000ull*256*4));
  float*  scores   = (float*)(ws + alloc(102000ull*4));
  float*  deltas   = (float*)(ws + alloc(102000ull*16));
  float*  top_s    = (float*)(ws + alloc(4000ull*4));
  u32*    top_idx  = (u32*)  (ws + alloc(4000ull*4));
  float*  cat_sc   = (float*)(ws + alloc(4000ull*4));
  float4* cat_bx   = (float4*)(ws + alloc(4000ull*16));
  float*  scores_s = (float*)(ws + alloc(4000ull*4));
  float4* boxes_s  = (float4*)(ws + alloc(4000ull*16));
  float4* obox     = (float4*)(ws + alloc(4000ull*16));
  u64*    mask     = (u64*)  (ws + alloc(4000ull*63*8));
  float4* props    = (float4*)(ws + alloc(150ull*16));
  float*  x0       = (float*)(ws + alloc(150ull*12544*4));
  float*  x1       = (float*)(ws + alloc(150ull*1024*4));
  float*  x2       = (float*)(ws + alloc(150ull*1024*4));
  float*  wcat     = (float*)(ws + alloc(105ull*1024*4));
  float*  bcat     = (float*)(ws + alloc(105ull*4));
  float*  convp    = (float*)(ws + alloc(36864000ull*4));
  float*  partial  = hid;

  hipLaunchKernelGGL(prep_k, dim3(996), dim3(256), 0, stream,
                     rpn_w, wT1, cls_w, cls_b, bbox_w, bbox_b, wcat, bcat);

  hipLaunchKernelGGL(rpn_conv_all_k, dim3(2416), dim3(256), 0, stream,
                     p[0], p[1], p[2], p[3], wT1, convp);

  hipLaunchKernelGGL(rpn_heads_k, dim3((34000+63)/64), dim3(256), 0, stream,
                     convp, rpn_b, obj_w, obj_b, del_w, del_b, scores, deltas);
  hipLaunchKernelGGL(topk_k, dim3(4), dim3(1024), 0, stream, scores, top_s, top_idx);
  hipLaunchKernelGGL(sort_k, dim3(1), dim3(1024), 0, stream, top_idx, top_s, deltas,
                     cat_sc, cat_bx, scores_s, boxes_s, obox);
  hipLaunchKernelGGL(iou_k, dim3(1000), dim3(64,4), 0, stream, obox, mask);
  hipLaunchKernelGGL(nms_scan_k, dim3(1), dim3(64), 0, stream, mask, scores_s, boxes_s, props);
  hipLaunchKernelGGL(roi_k, dim3(49,150), dim3(256), 0, stream, p[0],p[1],p[2],p[3], props, x0);

  hipLaunchKernelGGL(fc_split_k, dim3(16,5,28), dim3(256), 0, stream, x0, fc1_w, partial, 150, 1024, 12544, 448);
  hipLaunchKernelGGL(fc_reduce_k, dim3((150*1024+255)/256), dim3(256), 0, stream, partial, fc1_b, x1, 150, 1024, 28, 1);
  hipLaunchKernelGGL(fc_split_k, dim3(16,5,8), dim3(256), 0, stream, x1, fc2_w, partial, 150, 1024, 1024, 128);
  hipLaunchKernelGGL(fc_reduce_k, dim3((150*1024+255)/256), dim3(256), 0, stream, partial, fc2_b, x2, 150, 1024, 8, 1);
  hipLaunchKernelGGL(fc_split_k, dim3(2,5,8), dim3(256), 0, stream, x2, wcat, partial, 150, 105, 1024, 128);
  hipLaunchKernelGGL(fc_reduce_k, dim3((150*105+255)/256), dim3(256), 0, stream, partial, bcat, (float*)d_out, 150, 105, 8, 0);
}